// Round 17
// baseline (64.660 us; speedup 1.0000x reference)
//
#include <hip/hip_runtime.h>
#include <math.h>

#define DIM 256

// ---------------------------------------------------------------------------
// K0 setup (4 blocks, one per output qubit q): builds M[q] = T[q] reshaped as
// 16x16 over (j=p0*4+p1, k=p2*4+p3) into ws. Validated math (rounds 2-16).
// z_q(row) = sum_{j,k} u_j M[q][j][k] v_k,  u = a0(x)a1, v = a2(x)a3,
// a_i = (1, Ax_i, Ay_i, Az_i) Bloch components; depolarize folded as
// s^(1+nnz), s = 1-4*0.05/3.  Qubit q <-> index bit (3-q).
// ---------------------------------------------------------------------------
__global__ void qc_setup_kernel(const float* __restrict__ qw, float* __restrict__ T)
{
  __shared__ float Vr[16][16], Vi[16][16];
  __shared__ float Or[16][16], Oi[16][16];
  const int tid = threadIdx.x;
  const int r = tid >> 4, c = tid & 15;

  Vr[r][c] = (r == c) ? 1.0f : 0.0f;
  Vi[r][c] = 0.0f;
  __syncthreads();

  #pragma unroll 1
  for (int i = 0; i < 4; ++i) {
    const int cm = 8 >> i;             // control mask (qubit i)
    const int tm = 8 >> ((i + 1) & 3); // target mask (qubit (i+1)%4)
    // CNOT(control=i, target=(i+1)%4): row permutation
    {
      const int k = (r & cm) ? (r ^ tm) : r;
      const float nr = Vr[k][c], ni = Vi[k][c];
      __syncthreads();
      Vr[r][c] = nr; Vi[r][c] = ni;
      __syncthreads();
    }
    const float w  = qw[4 + i];        // qweights[1][i]
    const float ch = cosf(0.5f * w), sh = sinf(0.5f * w);
    // RY(w) on qubit i
    {
      const int m = 8 >> i;
      const int r0 = r & ~m, r1 = r | m;
      float u0, u1;
      if (r & m) { u0 = sh; u1 = ch; } else { u0 = ch; u1 = -sh; }
      const float nr = u0 * Vr[r0][c] + u1 * Vr[r1][c];
      const float ni = u0 * Vi[r0][c] + u1 * Vi[r1][c];
      __syncthreads();
      Vr[r][c] = nr; Vi[r][c] = ni;
      __syncthreads();
    }
    // RZ(w) on qubit i (diagonal)
    {
      const int m = 8 >> i;
      const float pr = ch;
      const float pi = (r & m) ? sh : -sh;
      const float vr = Vr[r][c], vi = Vi[r][c];
      Vr[r][c] = pr * vr - pi * vi;
      Vi[r][c] = pr * vi + pi * vr;
      __syncthreads();
    }
  }

  const int q  = blockIdx.x;           // one q per block
  const int zm = 8 >> q;
  // O[r][c] = sum_k conj(V[k][r]) * sign_q(k) * V[k][c]
  float orr = 0.0f, oii = 0.0f;
  for (int k = 0; k < 16; ++k) {
    const float sgn = (k & zm) ? -1.0f : 1.0f;
    const float ar = Vr[k][r], ai = -Vi[k][r];
    const float br = Vr[k][c], bi = Vi[k][c];
    orr += sgn * (ar * br - ai * bi);
    oii += sgn * (ar * bi + ai * br);
  }
  __syncthreads();
  Or[r][c] = orr; Oi[r][c] = oii;
  __syncthreads();

  // thread tid <-> Pauli string p; Tr(P O) = sum_n P[n][m(n)] * O[m(n)][n]
  const float sdep = 1.0f - 4.0f * 0.05f / 3.0f;
  const int p0 = tid >> 6, p1 = (tid >> 4) & 3, p2 = (tid >> 2) & 3, p3 = tid & 3;
  float tr = 0.0f;
  for (int n = 0; n < 16; ++n) {
    int m = n;
    float fr = 1.0f, fi = 0.0f;
    #pragma unroll
    for (int i2 = 0; i2 < 4; ++i2) {
      const int a   = (n >> (3 - i2)) & 1;
      const int pi_ = (i2 == 0) ? p0 : (i2 == 1) ? p1 : (i2 == 2) ? p2 : p3;
      if (pi_ == 1) {                    // X
        m ^= (8 >> i2);
      } else if (pi_ == 2) {             // Y
        m ^= (8 >> i2);
        const float s2  = a ? 1.0f : -1.0f;
        const float nfr = -fi * s2, nfi = fr * s2;
        fr = nfr; fi = nfi;
      } else if (pi_ == 3) {             // Z
        if (a) { fr = -fr; fi = -fi; }
      }
    }
    tr += fr * Or[m][n] - fi * Oi[m][n];
  }
  const int nnz = (p0 != 0) + (p1 != 0) + (p2 != 0) + (p3 != 0);
  float scale = 1.0f / 16.0f;
  for (int e = 0; e <= nnz; ++e) scale *= sdep;
  T[q * 256 + tid] = tr * scale;
}

// ---------------------------------------------------------------------------
// K1: angles GEMV. Pure streaming read of x (64MB), writes acc[B][4] (1MB).
// Grid-stride over row pairs; paired butterfly (proven r11-r14): prefold
// xor-32, pack two rows into half-waves, 5-step reduce serves both rows.
// 8192 waves -> loads for iteration n+1 pipeline under reduce of iteration n.
// ---------------------------------------------------------------------------
__global__ __launch_bounds__(256) void k1_angles(
    const float* __restrict__ x,
    const float* __restrict__ Win,
    float* __restrict__ acc,
    int B)
{
  const int lane = threadIdx.x & 63;
  const int wid  = blockIdx.x * (blockDim.x >> 6) + (threadIdx.x >> 6);
  const int nw   = gridDim.x * (blockDim.x >> 6);

  float4 winf[4];
  #pragma unroll
  for (int q = 0; q < 4; ++q)
    winf[q] = *reinterpret_cast<const float4*>(&Win[q * 256 + lane * 4]);

  const int npair = B >> 1;
  #pragma unroll 1
  for (int p = wid; p < npair; p += nw) {
    const size_t base = (size_t)p * 2 * DIM + lane * 4;
    const float4 xa = *reinterpret_cast<const float4*>(&x[base]);
    const float4 xb = *reinterpret_cast<const float4*>(&x[base + DIM]);

    float aA[4], aB[4];
    #pragma unroll
    for (int q = 0; q < 4; ++q) {
      aA[q] = xa.x * winf[q].x + xa.y * winf[q].y + xa.z * winf[q].z + xa.w * winf[q].w;
      aB[q] = xb.x * winf[q].x + xb.y * winf[q].y + xb.z * winf[q].z + xb.w * winf[q].w;
    }
    #pragma unroll
    for (int q = 0; q < 4; ++q) {
      aA[q] += __shfl_xor(aA[q], 32, 64);
      aB[q] += __shfl_xor(aB[q], 32, 64);
      aA[q] = (lane < 32) ? aA[q] : aB[q];
    }
    #pragma unroll
    for (int off = 1; off < 32; off <<= 1) {
      #pragma unroll
      for (int q = 0; q < 4; ++q) aA[q] += __shfl_xor(aA[q], off, 64);
    }
    if ((lane & 31) == 0) {
      const int row = p * 2 + (lane >> 5);
      *reinterpret_cast<float4*>(&acc[(size_t)row * 4]) =
          make_float4(aA[0], aA[1], aA[2], aA[3]);
    }
  }
}

// ---------------------------------------------------------------------------
// K2: middle. ONE THREAD PER ROW, zero redundancy, zero shuffles, zero LDS.
// Reads acc[B][4] (1MB), writes z[B][4] (1MB). tanh+LN+Bloch + full bilinear
// contraction z_q = sum_j u_j (M[q][j].v), M wave-uniform -> s_load.
// ---------------------------------------------------------------------------
__global__ __launch_bounds__(256) void k2_middle(
    const float* __restrict__ acc,
    const float* __restrict__ b_in,
    const float* __restrict__ gamma,
    const float* __restrict__ beta,
    const float* __restrict__ qw,
    const float* __restrict__ M,
    float* __restrict__ z,
    int B)
{
  const int g = blockIdx.x * blockDim.x + threadIdx.x;
  if (g >= B) return;

  const float4 av = *reinterpret_cast<const float4*>(&acc[(size_t)g * 4]);
  const float aq[4] = {av.x, av.y, av.z, av.w};

  float xp[4];
  #pragma unroll
  for (int q = 0; q < 4; ++q) {
    const float e = __expf(2.0f * (aq[q] + b_in[q]));
    xp[q] = 1.0f - __fdividef(2.0f, e + 1.0f);   // tanh, inf-safe
  }
  const float mu = 0.25f * (xp[0] + xp[1] + xp[2] + xp[3]);
  const float d0 = xp[0] - mu, d1 = xp[1] - mu, d2 = xp[2] - mu, d3 = xp[3] - mu;
  const float var = 0.25f * (d0 * d0 + d1 * d1 + d2 * d2 + d3 * d3);
  const float inv = rsqrtf(var + 1e-5f);

  float A0[4], A1[4], A2[4], A3[4];   // a_i = (1, Ax, Ay, Az)
  #pragma unroll
  for (int i = 0; i < 4; ++i) {
    const float w0 = qw[i], w1 = qw[4 + i];
    const float cwa = cosf(w0), swa = sinf(w0);
    const float cwb = cosf(w1), swb = sinf(w1);
    const float ang = ((i == 0 ? d0 : i == 1 ? d1 : i == 2 ? d2 : d3) * inv) * gamma[i] + beta[i];
    float sn, cs;
    __sincosf(ang, &sn, &cs);
    const float ax = sn * sn;                     // RX(t) then RZ(t)
    const float ay = -sn * cs;
    const float az = cs;
    const float ay2 = ay * cwa - az * swa;        // RX(w0)
    const float az2 = ay * swa + az * cwa;
    const float Axv = ax * cwb - ay2 * swb;       // RZ(w1)
    const float Ayv = ax * swb + ay2 * cwb;
    float* dst = (i == 0) ? A0 : (i == 1) ? A1 : (i == 2) ? A2 : A3;
    dst[0] = 1.0f; dst[1] = Axv; dst[2] = Ayv; dst[3] = az2;
  }

  float v[16];
  #pragma unroll
  for (int a = 0; a < 4; ++a)
    #pragma unroll
    for (int b = 0; b < 4; ++b)
      v[a * 4 + b] = A2[a] * A3[b];

  float zo[4];
  #pragma unroll
  for (int q = 0; q < 4; ++q) {
    float zq = 0.0f;
    #pragma unroll
    for (int j = 0; j < 16; ++j) {
      const float* Mr = &M[(q * 16 + j) * 16];   // wave-uniform -> s_load
      float w = 0.0f;
      #pragma unroll
      for (int k = 0; k < 16; ++k) w += Mr[k] * v[k];
      zq += (A0[j >> 2] * A1[j & 3]) * w;        // u_j inlined (static idx)
    }
    zo[q] = zq;
  }
  *reinterpret_cast<float4*>(&z[(size_t)g * 4]) =
      make_float4(zo[0], zo[1], zo[2], zo[3]);
}

// ---------------------------------------------------------------------------
// K3: epilogue. ONE THREAD PER OUTPUT FLOAT4 — a copy kernel with 16 FMA.
// Reads x (64MB, L3-hot from K1) + z[row] (broadcast) + Wout/b_out (L1),
// writes out (64MB). No reductions, no shuffles, no barriers; 65536 waves.
// ---------------------------------------------------------------------------
__global__ __launch_bounds__(256) void k3_epilogue(
    const float* __restrict__ x,
    const float* __restrict__ z,
    const float* __restrict__ Wout,
    const float* __restrict__ b_out,
    float* __restrict__ out,
    int B)
{
  const size_t g = (size_t)blockIdx.x * blockDim.x + threadIdx.x;  // float4 idx
  const int row = (int)(g >> 6);
  const int c4  = (int)(g & 63);
  if (row >= B) return;

  const float4 xv = *reinterpret_cast<const float4*>(&x[g * 4]);
  const float4 zv = *reinterpret_cast<const float4*>(&z[(size_t)row * 4]);
  const float4 w0 = *reinterpret_cast<const float4*>(&Wout[(c4 * 4 + 0) * 4]);
  const float4 w1 = *reinterpret_cast<const float4*>(&Wout[(c4 * 4 + 1) * 4]);
  const float4 w2 = *reinterpret_cast<const float4*>(&Wout[(c4 * 4 + 2) * 4]);
  const float4 w3 = *reinterpret_cast<const float4*>(&Wout[(c4 * 4 + 3) * 4]);
  const float4 bv = *reinterpret_cast<const float4*>(&b_out[c4 * 4]);

  float4 o;
  o.x = xv.x + bv.x + zv.x * w0.x + zv.y * w0.y + zv.z * w0.z + zv.w * w0.w;
  o.y = xv.y + bv.y + zv.x * w1.x + zv.y * w1.y + zv.z * w1.z + zv.w * w1.w;
  o.z = xv.z + bv.z + zv.x * w2.x + zv.y * w2.y + zv.z * w2.z + zv.w * w2.w;
  o.w = xv.w + bv.w + zv.x * w3.x + zv.y * w3.y + zv.z * w3.z + zv.w * w3.w;
  *reinterpret_cast<float4*>(&out[g * 4]) = o;
}

extern "C" void kernel_launch(void* const* d_in, const int* in_sizes, int n_in,
                              void* d_out, int out_size, void* d_ws, size_t ws_size,
                              hipStream_t stream)
{
  const float* x     = (const float*)d_in[0];
  const float* Win   = (const float*)d_in[1];
  const float* b_in  = (const float*)d_in[2];
  const float* gamma = (const float*)d_in[3];
  const float* beta  = (const float*)d_in[4];
  const float* qw    = (const float*)d_in[5];
  const float* Wout  = (const float*)d_in[6];
  const float* b_out = (const float*)d_in[7];
  float* out = (float*)d_out;
  const int B = in_sizes[0] / DIM;

  float* M   = (float*)d_ws;                 // 4*256 floats   = 4 KB
  float* acc = M + 1024;                     // B*4 floats     = 1 MB
  float* zbuf = acc + (size_t)B * 4;         // B*4 floats     = 1 MB

  hipLaunchKernelGGL(qc_setup_kernel, dim3(4), dim3(256), 0, stream, qw, M);

  // K1: 2048 blocks x 256 thr = 8192 waves, 4 row-pairs each.
  hipLaunchKernelGGL(k1_angles, dim3(2048), dim3(256), 0, stream, x, Win, acc, B);

  // K2: one thread per row.
  hipLaunchKernelGGL(k2_middle, dim3((B + 255) / 256), dim3(256), 0, stream,
                     acc, b_in, gamma, beta, qw, M, zbuf, B);

  // K3: one thread per output float4.
  const size_t nf4 = (size_t)B * 64;
  hipLaunchKernelGGL(k3_epilogue, dim3((unsigned)((nf4 + 255) / 256)), dim3(256),
                     0, stream, x, zbuf, Wout, b_out, out, B);
}